// Round 2
// baseline (466.383 us; speedup 1.0000x reference)
//
#include <hip/hip_runtime.h>
#include <stdint.h>

typedef unsigned short u16;

#define DIM 512
#define HIDN 1024
#define TT 4096
#define BB 8
#define MM 32768   // BB*TT
#define CH 128     // scan chunks
#define CL 32      // chunk length (CH*CL == TT)

// ---------- bf16 helpers ----------
__device__ __forceinline__ u16 f2bf(float f) {
  union { float f; uint32_t u; } v; v.f = f;
  uint32_t u = v.u;
  uint32_t r = u + 0x7fffu + ((u >> 16) & 1u);   // RTNE
  return (u16)(r >> 16);
}
__device__ __forceinline__ float bf2f(u16 h) {
  union { uint32_t u; float f; } v; v.u = ((uint32_t)h) << 16; return v.f;
}

typedef __bf16 bf16x8 __attribute__((ext_vector_type(8)));
typedef float f32x4 __attribute__((ext_vector_type(4)));

// ---------- prep: weights -> bf16, decay -> a/(1-a)/a^CL, convw -> [5][D] ----------
__global__ __launch_bounds__(256) void prep_kernel(
    const float* __restrict__ wout, const float* __restrict__ w1,
    const float* __restrict__ w2, const float* __restrict__ dl,
    const float* __restrict__ convw,
    u16* __restrict__ wout_h, u16* __restrict__ w1_h, u16* __restrict__ w2_h,
    float* __restrict__ a, float* __restrict__ oma, float* __restrict__ aL,
    float* __restrict__ convwT) {
  int i = blockIdx.x * 256 + threadIdx.x;
  if (i < DIM * DIM) wout_h[i] = f2bf(wout[i]);
  if (i < HIDN * DIM) { w1_h[i] = f2bf(w1[i]); w2_h[i] = f2bf(w2[i]); }
  if (i < 5 * DIM) {
    int kk = i / DIM, n = i - kk * DIM;
    convwT[i] = convw[n * 5 + kk];
  }
  if (i < DIM) {
    float av = 1.0f / (1.0f + expf(-dl[i]));
    a[i] = av; oma[i] = 1.0f - av; aL[i] = powf(av, (float)CL);
  }
}

// ---------- LayerNorm rows: fp32 in -> bf16 out (one wave per row) ----------
__global__ __launch_bounds__(256) void ln_rows(
    const float* __restrict__ xin, const float* __restrict__ g,
    const float* __restrict__ bvec, u16* __restrict__ out) {
  int lane = threadIdx.x & 63, wave = threadIdx.x >> 6;
  size_t row = (size_t)blockIdx.x * 4 + wave;
  const float4* xr = (const float4*)(xin + row * DIM);
  float4 v0 = xr[lane * 2 + 0];
  float4 v1 = xr[lane * 2 + 1];
  float s1 = v0.x + v0.y + v0.z + v0.w + v1.x + v1.y + v1.z + v1.w;
  float s2 = v0.x * v0.x + v0.y * v0.y + v0.z * v0.z + v0.w * v0.w
           + v1.x * v1.x + v1.y * v1.y + v1.z * v1.z + v1.w * v1.w;
#pragma unroll
  for (int o = 1; o < 64; o <<= 1) { s1 += __shfl_xor(s1, o); s2 += __shfl_xor(s2, o); }
  float mu = s1 * (1.0f / DIM);
  float var = s2 * (1.0f / DIM) - mu * mu;
  float rs = rsqrtf(var + 1e-5f);
  const float4* gr = (const float4*)g;
  const float4* br = (const float4*)bvec;
  float4 g0 = gr[lane * 2], g1 = gr[lane * 2 + 1];
  float4 b0 = br[lane * 2], b1 = br[lane * 2 + 1];
  uint32_t p0 = (uint32_t)f2bf((v0.x - mu) * rs * g0.x + b0.x) | ((uint32_t)f2bf((v0.y - mu) * rs * g0.y + b0.y) << 16);
  uint32_t p1 = (uint32_t)f2bf((v0.z - mu) * rs * g0.z + b0.z) | ((uint32_t)f2bf((v0.w - mu) * rs * g0.w + b0.w) << 16);
  uint32_t p2 = (uint32_t)f2bf((v1.x - mu) * rs * g1.x + b1.x) | ((uint32_t)f2bf((v1.y - mu) * rs * g1.y + b1.y) << 16);
  uint32_t p3 = (uint32_t)f2bf((v1.z - mu) * rs * g1.z + b1.z) | ((uint32_t)f2bf((v1.w - mu) * rs * g1.w + b1.w) << 16);
  uint4 pk; pk.x = p0; pk.y = p1; pk.z = p2; pk.w = p3;
  ((uint4*)(out + row * DIM))[lane] = pk;
}

// ---------- scan phase A: per-chunk local end states (2 channels/thread) ----------
__global__ __launch_bounds__(256) void scan_local(
    const u16* __restrict__ xn, const float* __restrict__ a,
    const float* __restrict__ oma, float* __restrict__ carry) {
  int idx = blockIdx.x * 256 + threadIdx.x;     // [b(3) | c(7) | dp(8)]
  int dp = (idx & 255) * 2;
  int c = (idx >> 8) & (CH - 1);
  int b = idx >> 15;
  float a0 = a[dp], a1 = a[dp + 1], o0 = oma[dp], o1 = oma[dp + 1];
  const uint32_t* xp = (const uint32_t*)(xn + ((size_t)(b * TT + c * CL)) * DIM + dp);
  float s0 = 0.f, s1 = 0.f;
#pragma unroll
  for (int i = 0; i < CL; ++i) {
    uint32_t u = xp[(size_t)i * (DIM / 2)];
    s0 = fmaf(a0, s0, o0 * bf2f((u16)(u & 0xffffu)));
    s1 = fmaf(a1, s1, o1 * bf2f((u16)(u >> 16)));
  }
  float2 cv; cv.x = s0; cv.y = s1;
  *(float2*)&carry[((size_t)(b * CH + c)) * DIM + dp] = cv;
}

// ---------- scan phase B: sequential scan over chunk carries ----------
__global__ __launch_bounds__(256) void scan_carry(
    const float* __restrict__ carry, const float* __restrict__ aL,
    float* __restrict__ start) {
  int idx = blockIdx.x * 256 + threadIdx.x;     // 0..4095: [b(3) | d(9)]
  int d = idx & (DIM - 1);
  int b = idx >> 9;
  float al = aL[d];
  float s = 0.f;
#pragma unroll 8
  for (int c = 0; c < CH; ++c) {
    size_t o = ((size_t)(b * CH + c)) * DIM + d;
    start[o] = s;
    s = fmaf(al, s, carry[o]);
  }
}

// ---------- scan phase C: replay with correct init, emit ss (2 channels/thread) ----------
__global__ __launch_bounds__(256) void scan_emit(
    const u16* __restrict__ xn, const float* __restrict__ a,
    const float* __restrict__ oma, const float* __restrict__ start,
    u16* __restrict__ ss) {
  int idx = blockIdx.x * 256 + threadIdx.x;     // [b(3) | c(7) | dp(8)]
  int dp = (idx & 255) * 2;
  int c = (idx >> 8) & (CH - 1);
  int b = idx >> 15;
  float a0 = a[dp], a1 = a[dp + 1], o0 = oma[dp], o1 = oma[dp + 1];
  const uint32_t* xp = (const uint32_t*)(xn + ((size_t)(b * TT + c * CL)) * DIM + dp);
  uint32_t* sp = (uint32_t*)(ss + ((size_t)(b * TT + c * CL)) * DIM + dp);
  float2 st = *(const float2*)&start[((size_t)(b * CH + c)) * DIM + dp];
  float s0 = st.x, s1 = st.y;
#pragma unroll
  for (int i = 0; i < CL; ++i) {
    uint32_t u = xp[(size_t)i * (DIM / 2)];
    s0 = fmaf(a0, s0, o0 * bf2f((u16)(u & 0xffffu)));
    s1 = fmaf(a1, s1, o1 * bf2f((u16)(u >> 16)));
    sp[(size_t)i * (DIM / 2)] = (uint32_t)f2bf(s0) | ((uint32_t)f2bf(s1) << 16);
  }
}

// ---------- 256x256-tile 8-wave MFMA GEMM, C[m,n] = sum_k A[m,k]*B[n,k] ----------
// 512 threads = 8 waves (2 M-waves x 4 N-waves), per-wave 128x64 output.
// BK=64, 128 KiB dynamic LDS, double-buffered. ONE barrier per K-tile.
// Per tile t (buf p = t&1):
//   1. stage t+1 -> buf p^1 (8 gload_lds; p^1's reads drained + barrier'd
//      last iter; issuing FIRST gives a full tile of landing window so the
//      tile-end vmcnt(0) is ~free)
//   2. ds_read B-frags (8) + A-quadrant0 (4) from buf p
//   3. for qd=0..3: { ds_read A-quadrant qd+1 ; setprio(1); 16 MFMA(Q qd);
//      setprio(0) }  -- reads of Q{qd+1} overlap MFMA of Q qd in program
//      order; compiler's fine-grained lgkmcnt keeps correctness (m97 r109).
//   4. lgkmcnt(0) vmcnt(0); s_barrier  -- all reads of p done (stage-safe
//      for next iter), t+1's LDS writes visible to all waves.
// EPI 0: out_f32 = acc + bias[n] + depthwise_conv(xn)[m,n] + convb[n] + resid  (-> x1)
// EPI 1: out_bf16 = gelu_exact(acc + bias[n])                                  (-> hg)
// EPI 2: out_f32 = acc + bias[n] + resid[m,n]                                  (-> d_out)
template <int Kd, int NCOL, int EPI>
__global__ __launch_bounds__(512, 2) void gemm_bt(
    const u16* __restrict__ A, const u16* __restrict__ Bmat,
    const float* __restrict__ bias, const float* __restrict__ resid,
    const u16* __restrict__ xn, const float* __restrict__ convwT,
    const float* __restrict__ convb, float* __restrict__ outf,
    u16* __restrict__ outh) {
  extern __shared__ __align__(16) u16 lds[];
  u16* sAb = lds;            // [2][256*64]
  u16* sBb = lds + 32768;    // [2][256*64]
  const int tid = threadIdx.x;
  const int lane = tid & 63, wave = tid >> 6;
  const int wm = wave >> 2;            // 0..1  -> 128-row strip
  const int wn = wave & 3;             // 0..3  -> 64-col strip
  const int rA = lane & 15, q = lane >> 4;
  const int lrow = lane >> 3;          // 0..7 rows within an 8-row group
  const int lslot = lane & 7;          // 16B slot within row
  const int gk = ((lslot ^ lrow) & 7) * 8;  // XOR-swizzled k offset (elements)

  // XCD swizzle: lin%8 ~ XCD id; rows partitioned by XCD, cols fast-varying.
  const int lin = blockIdx.x;
  const int tile_col = (lin >> 3) & (NCOL - 1);
  const int tile_row = (lin & 7) + 8 * ((lin >> 3) / NCOL);
  const size_t rowTile = (size_t)tile_row * 256;
  const size_t colTile = (size_t)tile_col * 256;

  const u16* Abase = A + rowTile * Kd;
  const u16* Bbase = Bmat + colTile * Kd;

  f32x4 acc[8][4];
#pragma unroll
  for (int i = 0; i < 8; i++)
#pragma unroll
    for (int j = 0; j < 4; j++) acc[i][j] = (f32x4){0.f, 0.f, 0.f, 0.f};

  // stage one full K-tile (A 32KiB + B 32KiB): 8 global_load_lds per thread
  auto stage = [&](int kt, int buf) {
#pragma unroll
    for (int j = 0; j < 4; ++j) {
      const int g = j * 8 + wave;          // 8-row group id, 0..31
      const u16* ga = Abase + (size_t)(g * 8 + lrow) * Kd + kt + gk;
      const u16* gb = Bbase + (size_t)(g * 8 + lrow) * Kd + kt + gk;
      __builtin_amdgcn_global_load_lds(
          (const __attribute__((address_space(1))) void*)ga,
          (__attribute__((address_space(3))) void*)(sAb + buf * 16384 + g * 512), 16, 0, 0);
      __builtin_amdgcn_global_load_lds(
          (const __attribute__((address_space(1))) void*)gb,
          (__attribute__((address_space(3))) void*)(sBb + buf * 16384 + g * 512), 16, 0, 0);
    }
  };

  constexpr int NT = Kd / 64;
  stage(0, 0);
  __asm__ __volatile__("s_waitcnt vmcnt(0)" ::: "memory");
  __asm__ __volatile__("s_barrier" ::: "memory");

  const int sw = rA & 7;
#pragma unroll 1
  for (int t = 0; t < NT; ++t) {
    const int p = t & 1;
    const u16* bufA = sAb + p * 16384 + (wm * 128 + rA) * 64;
    const u16* bufB = sBb + p * 16384 + (wn * 64 + rA) * 64;

    // 1. stage next tile into the other buffer (its readers drained last iter)
    if (t + 1 < NT) stage((t + 1) * 64, p ^ 1);

    // 2. B frags + A quadrant 0
    bf16x8 bfr[4][2], afr[8][2];
#pragma unroll
    for (int ni = 0; ni < 4; ++ni)
#pragma unroll
      for (int ks = 0; ks < 2; ++ks)
        bfr[ni][ks] = *(const bf16x8*)&bufB[ni * 1024 + (((ks * 4 + q) ^ sw) * 8)];
#pragma unroll
    for (int mi = 0; mi < 2; ++mi)
#pragma unroll
      for (int ks = 0; ks < 2; ++ks)
        afr[mi][ks] = *(const bf16x8*)&bufA[mi * 1024 + (((ks * 4 + q) ^ sw) * 8)];

    // 3. quadrant pipeline: read Q{qd+1} in program order before MFMA Q{qd}
#pragma unroll
    for (int qd = 0; qd < 4; ++qd) {
      if (qd < 3) {
#pragma unroll
        for (int mi = 2 * qd + 2; mi < 2 * qd + 4; ++mi)
#pragma unroll
          for (int ks = 0; ks < 2; ++ks)
            afr[mi][ks] = *(const bf16x8*)&bufA[mi * 1024 + (((ks * 4 + q) ^ sw) * 8)];
      }
      __builtin_amdgcn_s_setprio(1);
#pragma unroll
      for (int mi = 2 * qd; mi < 2 * qd + 2; ++mi)
#pragma unroll
        for (int ni = 0; ni < 4; ++ni)
#pragma unroll
          for (int ks = 0; ks < 2; ++ks)
            acc[mi][ni] = __builtin_amdgcn_mfma_f32_16x16x32_bf16(bfr[ni][ks], afr[mi][ks], acc[mi][ni], 0, 0, 0);
      __builtin_amdgcn_s_setprio(0);
    }

    // 4. single barrier per tile: my reads of p done, t+1's LDS writes visible
    __asm__ __volatile__("s_waitcnt lgkmcnt(0) vmcnt(0)" ::: "memory");
    __asm__ __volatile__("s_barrier" ::: "memory");
  }

  // ---- vectorized epilogue: lane owns (m, n0..n0+3) ----
#pragma unroll
  for (int mi = 0; mi < 8; ++mi) {
    size_t m = rowTile + wm * 128 + mi * 16 + rA;
#pragma unroll
    for (int ni = 0; ni < 4; ++ni) {
      int n0 = (int)colTile + wn * 64 + ni * 16 + q * 4;
      f32x4 v = acc[mi][ni];
      float4 bv = *(const float4*)&bias[n0];
      float val0 = v[0] + bv.x, val1 = v[1] + bv.y, val2 = v[2] + bv.z, val3 = v[3] + bv.w;
      if constexpr (EPI == 0) {
        int tt = (int)(m & (TT - 1));
        float4 cb = *(const float4*)&convb[n0];
        float4 rv = *(const float4*)&resid[m * DIM + n0];
        val0 += cb.x + rv.x; val1 += cb.y + rv.y; val2 += cb.z + rv.z; val3 += cb.w + rv.w;
#pragma unroll
        for (int kk = 0; kk < 5; ++kk) {
          int ttc = tt + kk - 2;
          if (ttc >= 0 && ttc < TT) {
            uint2 xv = *(const uint2*)&xn[(m + (size_t)kk - 2) * DIM + n0];
            float4 wv = *(const float4*)&convwT[kk * DIM + n0];
            val0 = fmaf(wv.x, bf2f((u16)(xv.x & 0xffffu)), val0);
            val1 = fmaf(wv.y, bf2f((u16)(xv.x >> 16)), val1);
            val2 = fmaf(wv.z, bf2f((u16)(xv.y & 0xffffu)), val2);
            val3 = fmaf(wv.w, bf2f((u16)(xv.y >> 16)), val3);
          }
        }
        float4 ov; ov.x = val0; ov.y = val1; ov.z = val2; ov.w = val3;
        *(float4*)&outf[m * DIM + n0] = ov;
      } else if constexpr (EPI == 1) {
        const float isq2 = 0.70710678118654752f;
        float g0 = 0.5f * val0 * (1.0f + erff(val0 * isq2));
        float g1 = 0.5f * val1 * (1.0f + erff(val1 * isq2));
        float g2 = 0.5f * val2 * (1.0f + erff(val2 * isq2));
        float g3 = 0.5f * val3 * (1.0f + erff(val3 * isq2));
        uint2 pk;
        pk.x = (uint32_t)f2bf(g0) | ((uint32_t)f2bf(g1) << 16);
        pk.y = (uint32_t)f2bf(g2) | ((uint32_t)f2bf(g3) << 16);
        *(uint2*)&outh[m * HIDN + n0] = pk;
      } else {
        float4 rv = *(const float4*)&resid[m * DIM + n0];
        float4 ov;
        ov.x = val0 + rv.x; ov.y = val1 + rv.y; ov.z = val2 + rv.z; ov.w = val3 + rv.w;
        *(float4*)&outf[m * DIM + n0] = ov;
      }
    }
  }
}

extern "C" void kernel_launch(void* const* d_in, const int* in_sizes, int n_in,
                              void* d_out, int out_size, void* d_ws, size_t ws_size,
                              hipStream_t stream) {
  const float* x      = (const float*)d_in[0];
  const float* dl     = (const float*)d_in[1];
  const float* W_out  = (const float*)d_in[2];
  const float* b_out  = (const float*)d_in[3];
  const float* conv_w = (const float*)d_in[4];
  const float* conv_b = (const float*)d_in[5];
  const float* ln1_g  = (const float*)d_in[6];
  const float* ln1_b  = (const float*)d_in[7];
  const float* ln2_g  = (const float*)d_in[8];
  const float* ln2_b  = (const float*)d_in[9];
  const float* W1     = (const float*)d_in[10];
  const float* b1     = (const float*)d_in[11];
  const float* W2     = (const float*)d_in[12];
  const float* b2     = (const float*)d_in[13];

  char* ws = (char*)d_ws;
  // small region (< 8 MiB)
  u16*   wout_h = (u16*)(ws + 0);                         // 512 KiB
  u16*   w1_h   = (u16*)(ws + 524288);                    // 1 MiB
  u16*   w2_h   = (u16*)(ws + 1572864);                   // 1 MiB
  float* a_buf  = (float*)(ws + 2621440);                 // 2 KiB
  float* oma    = (float*)(ws + 2623488);                 // 2 KiB
  float* aL     = (float*)(ws + 2625536);                 // 2 KiB
  float* convwT = (float*)(ws + 2627584);                 // 10 KiB
  float* carry  = (float*)(ws + (4u << 20));              // 2 MiB
  float* start  = (float*)(ws + 6291456);                 // 2 MiB
  // big regions
  u16*   xn  = (u16*)(ws + (8u << 20));                   // 32 MiB
  u16*   ssb = (u16*)(ws + (40u << 20));                  // 32 MiB
  float* x1  = (float*)(ws + (72u << 20));                // 64 MiB
  u16*   h   = (u16*)(ws + (136u << 20));                 // 32 MiB
  u16*   hg  = (u16*)(ws + (168u << 20));                 // 64 MiB

  float* out = (float*)d_out;

  // allow 128 KiB dynamic LDS (one-time, idempotent; host-side, capture-safe)
  hipFuncSetAttribute(reinterpret_cast<const void*>(&gemm_bt<512, 2, 0>),
                      hipFuncAttributeMaxDynamicSharedMemorySize, 131072);
  hipFuncSetAttribute(reinterpret_cast<const void*>(&gemm_bt<512, 4, 1>),
                      hipFuncAttributeMaxDynamicSharedMemorySize, 131072);
  hipFuncSetAttribute(reinterpret_cast<const void*>(&gemm_bt<1024, 2, 2>),
                      hipFuncAttributeMaxDynamicSharedMemorySize, 131072);

  prep_kernel<<<2048, 256, 0, stream>>>(W_out, W1, W2, dl, conv_w, wout_h, w1_h, w2_h, a_buf, oma, aL, convwT);
  ln_rows<<<MM / 4, 256, 0, stream>>>(x, ln1_g, ln1_b, xn);
  scan_local<<<(BB * CH * DIM / 2) / 256, 256, 0, stream>>>(xn, a_buf, oma, carry);
  scan_carry<<<(BB * DIM) / 256, 256, 0, stream>>>(carry, aL, start);
  scan_emit<<<(BB * CH * DIM / 2) / 256, 256, 0, stream>>>(xn, a_buf, oma, start, ssb);
  gemm_bt<512, 2, 0><<<256, 512, 131072, stream>>>(ssb, wout_h, b_out, x, xn, convwT, conv_b, x1, nullptr);
  ln_rows<<<MM / 4, 256, 0, stream>>>(x1, ln2_g, ln2_b, h);
  gemm_bt<512, 4, 1><<<512, 512, 131072, stream>>>(h, w1_h, b1, nullptr, nullptr, nullptr, nullptr, nullptr, hg);
  gemm_bt<1024, 2, 2><<<256, 512, 131072, stream>>>(hg, w2_h, b2, x1, nullptr, nullptr, nullptr, out, nullptr);
}

// Round 4
// 393.552 us; speedup vs baseline: 1.1851x; 1.1851x over previous
//
#include <hip/hip_runtime.h>
#include <stdint.h>

typedef unsigned short u16;

#define DIM 512
#define HIDN 1024
#define TT 4096
#define BB 8
#define MM 32768   // BB*TT
#define CH 128     // scan chunks
#define CL 32      // chunk length (CH*CL == TT)

// ---------- bf16 helpers ----------
__device__ __forceinline__ u16 f2bf(float f) {
  union { float f; uint32_t u; } v; v.f = f;
  uint32_t u = v.u;
  uint32_t r = u + 0x7fffu + ((u >> 16) & 1u);   // RTNE
  return (u16)(r >> 16);
}
__device__ __forceinline__ float bf2f(u16 h) {
  union { uint32_t u; float f; } v; v.u = ((uint32_t)h) << 16; return v.f;
}

typedef __bf16 bf16x8 __attribute__((ext_vector_type(8)));
typedef float f32x4 __attribute__((ext_vector_type(4)));

// ---------- prep: weights -> bf16, decay -> a/(1-a)/a^CL, convw -> [5][D] ----------
__global__ __launch_bounds__(256) void prep_kernel(
    const float* __restrict__ wout, const float* __restrict__ w1,
    const float* __restrict__ w2, const float* __restrict__ dl,
    const float* __restrict__ convw,
    u16* __restrict__ wout_h, u16* __restrict__ w1_h, u16* __restrict__ w2_h,
    float* __restrict__ a, float* __restrict__ oma, float* __restrict__ aL,
    float* __restrict__ convwT) {
  int i = blockIdx.x * 256 + threadIdx.x;
  if (i < DIM * DIM) wout_h[i] = f2bf(wout[i]);
  if (i < HIDN * DIM) { w1_h[i] = f2bf(w1[i]); w2_h[i] = f2bf(w2[i]); }
  if (i < 5 * DIM) {
    int kk = i / DIM, n = i - kk * DIM;
    convwT[i] = convw[n * 5 + kk];
  }
  if (i < DIM) {
    float av = 1.0f / (1.0f + expf(-dl[i]));
    a[i] = av; oma[i] = 1.0f - av; aL[i] = powf(av, (float)CL);
  }
}

// ---------- LayerNorm rows: fp32 in -> bf16 out (one wave per row) ----------
__global__ __launch_bounds__(256) void ln_rows(
    const float* __restrict__ xin, const float* __restrict__ g,
    const float* __restrict__ bvec, u16* __restrict__ out) {
  int lane = threadIdx.x & 63, wave = threadIdx.x >> 6;
  size_t row = (size_t)blockIdx.x * 4 + wave;
  const float4* xr = (const float4*)(xin + row * DIM);
  float4 v0 = xr[lane * 2 + 0];
  float4 v1 = xr[lane * 2 + 1];
  float s1 = v0.x + v0.y + v0.z + v0.w + v1.x + v1.y + v1.z + v1.w;
  float s2 = v0.x * v0.x + v0.y * v0.y + v0.z * v0.z + v0.w * v0.w
           + v1.x * v1.x + v1.y * v1.y + v1.z * v1.z + v1.w * v1.w;
#pragma unroll
  for (int o = 1; o < 64; o <<= 1) { s1 += __shfl_xor(s1, o); s2 += __shfl_xor(s2, o); }
  float mu = s1 * (1.0f / DIM);
  float var = s2 * (1.0f / DIM) - mu * mu;
  float rs = rsqrtf(var + 1e-5f);
  const float4* gr = (const float4*)g;
  const float4* br = (const float4*)bvec;
  float4 g0 = gr[lane * 2], g1 = gr[lane * 2 + 1];
  float4 b0 = br[lane * 2], b1 = br[lane * 2 + 1];
  uint32_t p0 = (uint32_t)f2bf((v0.x - mu) * rs * g0.x + b0.x) | ((uint32_t)f2bf((v0.y - mu) * rs * g0.y + b0.y) << 16);
  uint32_t p1 = (uint32_t)f2bf((v0.z - mu) * rs * g0.z + b0.z) | ((uint32_t)f2bf((v0.w - mu) * rs * g0.w + b0.w) << 16);
  uint32_t p2 = (uint32_t)f2bf((v1.x - mu) * rs * g1.x + b1.x) | ((uint32_t)f2bf((v1.y - mu) * rs * g1.y + b1.y) << 16);
  uint32_t p3 = (uint32_t)f2bf((v1.z - mu) * rs * g1.z + b1.z) | ((uint32_t)f2bf((v1.w - mu) * rs * g1.w + b1.w) << 16);
  uint4 pk; pk.x = p0; pk.y = p1; pk.z = p2; pk.w = p3;
  ((uint4*)(out + row * DIM))[lane] = pk;
}

// ---------- scan phase A: per-chunk local end states (2 channels/thread) ----------
__global__ __launch_bounds__(256) void scan_local(
    const u16* __restrict__ xn, const float* __restrict__ a,
    const float* __restrict__ oma, float* __restrict__ carry) {
  int idx = blockIdx.x * 256 + threadIdx.x;     // [b(3) | c(7) | dp(8)]
  int dp = (idx & 255) * 2;
  int c = (idx >> 8) & (CH - 1);
  int b = idx >> 15;
  float a0 = a[dp], a1 = a[dp + 1], o0 = oma[dp], o1 = oma[dp + 1];
  const uint32_t* xp = (const uint32_t*)(xn + ((size_t)(b * TT + c * CL)) * DIM + dp);
  float s0 = 0.f, s1 = 0.f;
#pragma unroll
  for (int i = 0; i < CL; ++i) {
    uint32_t u = xp[(size_t)i * (DIM / 2)];
    s0 = fmaf(a0, s0, o0 * bf2f((u16)(u & 0xffffu)));
    s1 = fmaf(a1, s1, o1 * bf2f((u16)(u >> 16)));
  }
  float2 cv; cv.x = s0; cv.y = s1;
  *(float2*)&carry[((size_t)(b * CH + c)) * DIM + dp] = cv;
}

// ---------- scan phase B: sequential scan over chunk carries ----------
__global__ __launch_bounds__(256) void scan_carry(
    const float* __restrict__ carry, const float* __restrict__ aL,
    float* __restrict__ start) {
  int idx = blockIdx.x * 256 + threadIdx.x;     // 0..4095: [b(3) | d(9)]
  int d = idx & (DIM - 1);
  int b = idx >> 9;
  float al = aL[d];
  float s = 0.f;
#pragma unroll 8
  for (int c = 0; c < CH; ++c) {
    size_t o = ((size_t)(b * CH + c)) * DIM + d;
    start[o] = s;
    s = fmaf(al, s, carry[o]);
  }
}

// ---------- scan phase C: replay with correct init, emit ss (2 channels/thread) ----------
__global__ __launch_bounds__(256) void scan_emit(
    const u16* __restrict__ xn, const float* __restrict__ a,
    const float* __restrict__ oma, const float* __restrict__ start,
    u16* __restrict__ ss) {
  int idx = blockIdx.x * 256 + threadIdx.x;     // [b(3) | c(7) | dp(8)]
  int dp = (idx & 255) * 2;
  int c = (idx >> 8) & (CH - 1);
  int b = idx >> 15;
  float a0 = a[dp], a1 = a[dp + 1], o0 = oma[dp], o1 = oma[dp + 1];
  const uint32_t* xp = (const uint32_t*)(xn + ((size_t)(b * TT + c * CL)) * DIM + dp);
  uint32_t* sp = (uint32_t*)(ss + ((size_t)(b * TT + c * CL)) * DIM + dp);
  float2 st = *(const float2*)&start[((size_t)(b * CH + c)) * DIM + dp];
  float s0 = st.x, s1 = st.y;
#pragma unroll
  for (int i = 0; i < CL; ++i) {
    uint32_t u = xp[(size_t)i * (DIM / 2)];
    s0 = fmaf(a0, s0, o0 * bf2f((u16)(u & 0xffffu)));
    s1 = fmaf(a1, s1, o1 * bf2f((u16)(u >> 16)));
    sp[(size_t)i * (DIM / 2)] = (uint32_t)f2bf(s0) | ((uint32_t)f2bf(s1) << 16);
  }
}

// ---------- 256x256-tile 8-wave MFMA GEMM, 4-slot LDS ring, BK=32 ----------
// C[m,n] = sum_k A[m,k]*B[n,k].  512 thr = 8 waves (2M x 4N), per-wave 128x64.
// LDS: 4 ring slots x (A 256x32 + B 256x32) bf16 = 128 KiB. Tile t -> slot t&3;
// staging runs 3 TILES AHEAD. ONE barrier per tile:
//   [ds_read t (12 b128) ; stage t+3 (4 gload_lds) ; 32 MFMA]
//   -> vmcnt(counted) -> lgkmcnt(0) -> s_barrier
// Wait ordering (race-free, fixes r3): the counted vmcnt confirms MY tile-t+1
// loads landed BEFORE the barrier; the barrier then certifies ALL waves' t+1
// loads landed, so next iteration's ds_reads are safe. Steady-state vmcnt(8)
// (2 newer tiles stay in flight; never drains to 0 until the last 2 tiles --
// fixes r2). Ring reuse: reads of slot t&3 drained (lgkmcnt(0)) before the
// tile-t barrier; next write into that slot is staged in tile t+1 (= after).
// No barrier between reads and MFMA -> the 2 waves/SIMD de-phase, overlapping
// one wave's LDS reads with the other's MFMA burst.
// LDS layout (per slot, per matrix): row-major 256x32 bf16, 16B-slot index
// XOR-swizzled: phys_slot = s ^ (row&3) ^ ((row>>2)&3)  -> 2-way banks (free).
// Staged via pre-swizzled GLOBAL source + linear LDS dest (G21).
// EPI 0: out = acc + bias + depthwise_conv(xn) + convb + resid   (-> x1)
// EPI 1: out_bf16 = gelu_exact(acc + bias)                       (-> hg)
// EPI 2: out = acc + bias + resid                                (-> d_out)
template <int Kd, int NCOL, int EPI>
__global__ __launch_bounds__(512, 2) void gemm_bt(
    const u16* __restrict__ A, const u16* __restrict__ Bmat,
    const float* __restrict__ bias, const float* __restrict__ resid,
    const u16* __restrict__ xn, const float* __restrict__ convwT,
    const float* __restrict__ convb, float* __restrict__ outf,
    u16* __restrict__ outh) {
  extern __shared__ __align__(16) u16 lds[];
  u16* sA = lds;             // 4 slots x 8192 u16 (16 KiB each)
  u16* sB = lds + 32768;     // 4 slots x 8192 u16
  const int tid = threadIdx.x;
  const int lane = tid & 63, wave = tid >> 6;
  const int wm = wave >> 2;            // 0..1  -> 128-row strip
  const int wn = wave & 3;             // 0..3  -> 64-col strip
  const int rA = lane & 15, q = lane >> 4;

  // staging lane decomposition: 4 lanes per row, 16 rows per load-inst
  const int lrow4 = lane >> 2;                                   // 0..15
  const int sg = (lane & 3) ^ ((lane >> 2) & 3) ^ ((lane >> 4) & 3);  // swizzled 16B slot

  // XCD swizzle: lin%8 ~ XCD id; rows partitioned by XCD, cols fast-varying.
  const int lin = blockIdx.x;
  const int tile_col = (lin >> 3) & (NCOL - 1);
  const int tile_row = (lin & 7) + 8 * ((lin >> 3) / NCOL);
  const size_t rowTile = (size_t)tile_row * 256;
  const size_t colTile = (size_t)tile_col * 256;

  const u16* Abase = A + rowTile * Kd;
  const u16* Bbase = Bmat + colTile * Kd;

  f32x4 acc[8][4];
#pragma unroll
  for (int i = 0; i < 8; i++)
#pragma unroll
    for (int j = 0; j < 4; j++) acc[i][j] = (f32x4){0.f, 0.f, 0.f, 0.f};

  // stage A/B tiles of tile t: 2 load-insts each (rows 0..127, 128..255)
  auto stageA = [&](int t) {
    const int b = t & 3;
#pragma unroll
    for (int r = 0; r < 2; ++r) {
      const int rb = r * 128 + wave * 16;
      const u16* ga = Abase + (size_t)(rb + lrow4) * Kd + t * 32 + sg * 8;
      __builtin_amdgcn_global_load_lds(
          (const __attribute__((address_space(1))) void*)ga,
          (__attribute__((address_space(3))) void*)(sA + b * 8192 + rb * 32 + lane * 8), 16, 0, 0);
    }
  };
  auto stageB = [&](int t) {
    const int b = t & 3;
#pragma unroll
    for (int r = 0; r < 2; ++r) {
      const int rb = r * 128 + wave * 16;
      const u16* gb = Bbase + (size_t)(rb + lrow4) * Kd + t * 32 + sg * 8;
      __builtin_amdgcn_global_load_lds(
          (const __attribute__((address_space(1))) void*)gb,
          (__attribute__((address_space(3))) void*)(sB + b * 8192 + rb * 32 + lane * 8), 16, 0, 0);
    }
  };

  constexpr int NT = Kd / 32;
  // prologue: stage tiles 0,1,2 tile-major (12 load-insts -> exact vmcnt map)
  stageA(0); stageB(0);
  stageA(1); stageB(1);
  stageA(2); stageB(2);
  __asm__ __volatile__("s_waitcnt vmcnt(8)" ::: "memory");  // own tile-0 loads done
  __asm__ __volatile__("s_barrier" ::: "memory");           // => ALL tile-0 loads done

  const int ps = (q ^ (rA & 3) ^ ((rA >> 2) & 3)) * 8;   // per-lane phys 16B slot (u16 units)

#pragma unroll 1
  for (int t = 0; t < NT; ++t) {
    const int slot = t & 3;
    const u16* bA = sA + slot * 8192 + (wm * 128 + rA) * 32 + ps;
    const u16* bB = sB + slot * 8192 + (wn * 64 + rA) * 32 + ps;
    bf16x8 bfr[4], afr[8];
#pragma unroll
    for (int ni = 0; ni < 4; ++ni) bfr[ni] = *(const bf16x8*)&bB[ni * 512];
#pragma unroll
    for (int mi = 0; mi < 8; ++mi) afr[mi] = *(const bf16x8*)&bA[mi * 512];

    if (t + 3 < NT) { stageA(t + 3); stageB(t + 3); }

    __builtin_amdgcn_s_setprio(1);
#pragma unroll
    for (int mi = 0; mi < 8; ++mi)
#pragma unroll
      for (int ni = 0; ni < 4; ++ni)
        acc[mi][ni] = __builtin_amdgcn_mfma_f32_16x16x32_bf16(bfr[ni], afr[mi], acc[mi][ni], 0, 0, 0);
    __builtin_amdgcn_s_setprio(0);

    // counted wait: confirm tile t+1 landed (own wave) BEFORE the barrier
    if (t < NT - 3) {
      __asm__ __volatile__("s_waitcnt vmcnt(8)" ::: "memory");
    } else if (t == NT - 3) {
      __asm__ __volatile__("s_waitcnt vmcnt(4)" ::: "memory");
    } else if (t == NT - 2) {
      __asm__ __volatile__("s_waitcnt vmcnt(0)" ::: "memory");
    }
    __asm__ __volatile__("s_waitcnt lgkmcnt(0)" ::: "memory");  // my reads of slot drained
    __asm__ __volatile__("s_barrier" ::: "memory");
  }

  // ---- vectorized epilogue: lane owns (m, n0..n0+3) ----
#pragma unroll
  for (int mi = 0; mi < 8; ++mi) {
    size_t m = rowTile + wm * 128 + mi * 16 + rA;
#pragma unroll
    for (int ni = 0; ni < 4; ++ni) {
      int n0 = (int)colTile + wn * 64 + ni * 16 + q * 4;
      f32x4 v = acc[mi][ni];
      float4 bv = *(const float4*)&bias[n0];
      float val0 = v[0] + bv.x, val1 = v[1] + bv.y, val2 = v[2] + bv.z, val3 = v[3] + bv.w;
      if constexpr (EPI == 0) {
        int tt = (int)(m & (TT - 1));
        float4 cb = *(const float4*)&convb[n0];
        float4 rv = *(const float4*)&resid[m * DIM + n0];
        val0 += cb.x + rv.x; val1 += cb.y + rv.y; val2 += cb.z + rv.z; val3 += cb.w + rv.w;
#pragma unroll
        for (int kk = 0; kk < 5; ++kk) {
          int ttc = tt + kk - 2;
          if (ttc >= 0 && ttc < TT) {
            uint2 xv = *(const uint2*)&xn[(m + (size_t)kk - 2) * DIM + n0];
            float4 wv = *(const float4*)&convwT[kk * DIM + n0];
            val0 = fmaf(wv.x, bf2f((u16)(xv.x & 0xffffu)), val0);
            val1 = fmaf(wv.y, bf2f((u16)(xv.x >> 16)), val1);
            val2 = fmaf(wv.z, bf2f((u16)(xv.y & 0xffffu)), val2);
            val3 = fmaf(wv.w, bf2f((u16)(xv.y >> 16)), val3);
          }
        }
        float4 ov; ov.x = val0; ov.y = val1; ov.z = val2; ov.w = val3;
        *(float4*)&outf[m * DIM + n0] = ov;
      } else if constexpr (EPI == 1) {
        const float isq2 = 0.70710678118654752f;
        float g0 = 0.5f * val0 * (1.0f + erff(val0 * isq2));
        float g1 = 0.5f * val1 * (1.0f + erff(val1 * isq2));
        float g2 = 0.5f * val2 * (1.0f + erff(val2 * isq2));
        float g3 = 0.5f * val3 * (1.0f + erff(val3 * isq2));
        uint2 pk;
        pk.x = (uint32_t)f2bf(g0) | ((uint32_t)f2bf(g1) << 16);
        pk.y = (uint32_t)f2bf(g2) | ((uint32_t)f2bf(g3) << 16);
        *(uint2*)&outh[m * HIDN + n0] = pk;
      } else {
        float4 rv = *(const float4*)&resid[m * DIM + n0];
        float4 ov;
        ov.x = val0 + rv.x; ov.y = val1 + rv.y; ov.z = val2 + rv.z; ov.w = val3 + rv.w;
        *(float4*)&outf[m * DIM + n0] = ov;
      }
    }
  }
}

extern "C" void kernel_launch(void* const* d_in, const int* in_sizes, int n_in,
                              void* d_out, int out_size, void* d_ws, size_t ws_size,
                              hipStream_t stream) {
  const float* x      = (const float*)d_in[0];
  const float* dl     = (const float*)d_in[1];
  const float* W_out  = (const float*)d_in[2];
  const float* b_out  = (const float*)d_in[3];
  const float* conv_w = (const float*)d_in[4];
  const float* conv_b = (const float*)d_in[5];
  const float* ln1_g  = (const float*)d_in[6];
  const float* ln1_b  = (const float*)d_in[7];
  const float* ln2_g  = (const float*)d_in[8];
  const float* ln2_b  = (const float*)d_in[9];
  const float* W1     = (const float*)d_in[10];
  const float* b1     = (const float*)d_in[11];
  const float* W2     = (const float*)d_in[12];
  const float* b2     = (const float*)d_in[13];

  char* ws = (char*)d_ws;
  // small region (< 8 MiB)
  u16*   wout_h = (u16*)(ws + 0);                         // 512 KiB
  u16*   w1_h   = (u16*)(ws + 524288);                    // 1 MiB
  u16*   w2_h   = (u16*)(ws + 1572864);                   // 1 MiB
  float* a_buf  = (float*)(ws + 2621440);                 // 2 KiB
  float* oma    = (float*)(ws + 2623488);                 // 2 KiB
  float* aL     = (float*)(ws + 2625536);                 // 2 KiB
  float* convwT = (float*)(ws + 2627584);                 // 10 KiB
  float* carry  = (float*)(ws + (4u << 20));              // 2 MiB
  float* start  = (float*)(ws + 6291456);                 // 2 MiB
  // big regions
  u16*   xn  = (u16*)(ws + (8u << 20));                   // 32 MiB
  u16*   ssb = (u16*)(ws + (40u << 20));                  // 32 MiB
  float* x1  = (float*)(ws + (72u << 20));                // 64 MiB
  u16*   h   = (u16*)(ws + (136u << 20));                 // 32 MiB
  u16*   hg  = (u16*)(ws + (168u << 20));                 // 64 MiB

  float* out = (float*)d_out;

  // allow 128 KiB dynamic LDS (host-side, capture-safe)
  hipFuncSetAttribute(reinterpret_cast<const void*>(&gemm_bt<512, 2, 0>),
                      hipFuncAttributeMaxDynamicSharedMemorySize, 131072);
  hipFuncSetAttribute(reinterpret_cast<const void*>(&gemm_bt<512, 4, 1>),
                      hipFuncAttributeMaxDynamicSharedMemorySize, 131072);
  hipFuncSetAttribute(reinterpret_cast<const void*>(&gemm_bt<1024, 2, 2>),
                      hipFuncAttributeMaxDynamicSharedMemorySize, 131072);

  prep_kernel<<<2048, 256, 0, stream>>>(W_out, W1, W2, dl, conv_w, wout_h, w1_h, w2_h, a_buf, oma, aL, convwT);
  ln_rows<<<MM / 4, 256, 0, stream>>>(x, ln1_g, ln1_b, xn);
  scan_local<<<(BB * CH * DIM / 2) / 256, 256, 0, stream>>>(xn, a_buf, oma, carry);
  scan_carry<<<(BB * DIM) / 256, 256, 0, stream>>>(carry, aL, start);
  scan_emit<<<(BB * CH * DIM / 2) / 256, 256, 0, stream>>>(xn, a_buf, oma, start, ssb);
  gemm_bt<512, 2, 0><<<256, 512, 131072, stream>>>(ssb, wout_h, b_out, x, xn, convwT, conv_b, x1, nullptr);
  ln_rows<<<MM / 4, 256, 0, stream>>>(x1, ln2_g, ln2_b, h);
  gemm_bt<512, 4, 1><<<512, 512, 131072, stream>>>(h, w1_h, b1, nullptr, nullptr, nullptr, nullptr, nullptr, hg);
  gemm_bt<1024, 2, 2><<<256, 512, 131072, stream>>>(hg, w2_h, b2, x1, nullptr, nullptr, nullptr, out, nullptr);
}